// Round 1
// baseline (173.544 us; speedup 1.0000x reference)
//
#include <hip/hip_runtime.h>
#include <math.h>

#define NPTS 21
#define FLB  63          // floats per batch per tensor (21*3)
#define BPB  128         // batches per block (one thread per batch)
#define THREADS 128

__global__ void pa_init(float* out) {
    if (threadIdx.x == 0 && blockIdx.x == 0) out[0] = 0.0f;
}

__global__ __launch_bounds__(THREADS, 2)
void pa_mpjpe(const float* __restrict__ pred,
              const float* __restrict__ targ,
              float* __restrict__ out,
              int B, float inv_total)
{
    // stride-63 layout: odd stride -> at most 2-way LDS bank aliasing (free)
    __shared__ __align__(16) float sbuf[BPB * FLB];   // 32256 B
    __shared__ float swsum[THREADS / 64];

    const int tid  = threadIdx.x;
    const int b0   = blockIdx.x * BPB;
    const int nb   = (B - b0 < BPB) ? (B - b0) : BPB;
    const int nflt = nb * FLB;
    const int nvec = nflt >> 2;

    // ---- stage PRED chunk into LDS (coalesced float4; block base 16B-aligned) ----
    {
        const float4* g = (const float4*)(pred + (size_t)b0 * FLB);
        float4* s = (float4*)sbuf;
        for (int i = tid; i < nvec; i += THREADS) s[i] = g[i];
        const float* gf = pred + (size_t)b0 * FLB;
        for (int i = (nvec << 2) + tid; i < nflt; i += THREADS) sbuf[i] = gf[i];
    }
    __syncthreads();

    // ---- pred -> registers, accumulate raw moments ----
    float y[NPTS][3];
    float sy0 = 0.f, sy1 = 0.f, sy2 = 0.f, syy = 0.f;
    const int base = tid * FLB;
    #pragma unroll
    for (int n = 0; n < NPTS; ++n) {
        float a = sbuf[base + 3*n + 0];
        float b = sbuf[base + 3*n + 1];
        float c = sbuf[base + 3*n + 2];
        y[n][0] = a; y[n][1] = b; y[n][2] = c;
        sy0 += a; sy1 += b; sy2 += c;
        syy = fmaf(a, a, fmaf(b, b, fmaf(c, c, syy)));
    }
    __syncthreads();

    // ---- stage TARG chunk into the SAME LDS buffer ----
    {
        const float4* g = (const float4*)(targ + (size_t)b0 * FLB);
        float4* s = (float4*)sbuf;
        for (int i = tid; i < nvec; i += THREADS) s[i] = g[i];
        const float* gf = targ + (size_t)b0 * FLB;
        for (int i = (nvec << 2) + tid; i < nflt; i += THREADS) sbuf[i] = gf[i];
    }
    __syncthreads();

    // ---- targ stats + raw cross-covariance M[i][j] = sum_n x_i * y_j ----
    float sx0 = 0.f, sx1 = 0.f, sx2 = 0.f;
    float m00=0,m01=0,m02=0, m10=0,m11=0,m12=0, m20=0,m21=0,m22=0;
    #pragma unroll
    for (int n = 0; n < NPTS; ++n) {
        float a = sbuf[base + 3*n + 0];
        float b = sbuf[base + 3*n + 1];
        float c = sbuf[base + 3*n + 2];
        sx0 += a; sx1 += b; sx2 += c;
        float u = y[n][0], v = y[n][1], w = y[n][2];
        m00 = fmaf(a,u,m00); m01 = fmaf(a,v,m01); m02 = fmaf(a,w,m02);
        m10 = fmaf(b,u,m10); m11 = fmaf(b,v,m11); m12 = fmaf(b,w,m12);
        m20 = fmaf(c,u,m20); m21 = fmaf(c,v,m21); m22 = fmaf(c,w,m22);
    }

    const float invN = 1.0f / (float)NPTS;
    float mux0 = sx0*invN, mux1 = sx1*invN, mux2 = sx2*invN;
    float muy0 = sy0*invN, muy1 = sy1*invN, muy2 = sy2*invN;
    float ny2  = syy - (sy0*sy0 + sy1*sy1 + sy2*sy2) * invN;   // ||Y0||_F^2
    // centered cross-cov (rows: targ dims i, cols: pred dims j)
    float c00 = m00 - sx0*sy0*invN, c01 = m01 - sx0*sy1*invN, c02 = m02 - sx0*sy2*invN;
    float c10 = m10 - sx1*sy0*invN, c11 = m11 - sx1*sy1*invN, c12 = m12 - sx1*sy2*invN;
    float c20 = m20 - sx2*sy0*invN, c21 = m21 - sx2*sy1*invN, c22 = m22 - sx2*sy2*invN;

    // ---- orthogonal polar factor of A = Mc^T via det-scaled Newton ----
    // A = V S U^T  =>  polar Q = V U^T (exactly the reference's rotation,
    // reflection allowed), tr(P) = sum of singular values = <Q, A>_F.
    // Scale-invariant: skip normX/normY normalization entirely.
    float q00=c00, q01=c10, q02=c20,
          q10=c01, q11=c11, q12=c21,
          q20=c02, q21=c12, q22=c22;
    #pragma unroll
    for (int it = 0; it < 8; ++it) {
        // cofactor matrix C:  Q^{-T} = C / det
        float C00 = q11*q22 - q12*q21;
        float C01 = q12*q20 - q10*q22;
        float C02 = q10*q21 - q11*q20;
        float C10 = q02*q21 - q01*q22;
        float C11 = q00*q22 - q02*q20;
        float C12 = q01*q20 - q00*q21;
        float C20 = q01*q12 - q02*q11;
        float C21 = q02*q10 - q00*q12;
        float C22 = q00*q11 - q01*q10;
        float det = q00*C00 + q01*C01 + q02*C02;
        float ad  = fmaxf(fabsf(det), 1e-30f);
        float sdet = copysignf(ad, det);
        float g  = __expf(0.333333333f * __logf(ad));   // |det|^{1/3}; gamma precision non-critical
        float ha = 0.5f / g;                            // 0.5 * gamma
        float hb = 0.5f * g / sdet;                     // 0.5 * gamma^{-1} / det
        q00 = ha*q00 + hb*C00; q01 = ha*q01 + hb*C01; q02 = ha*q02 + hb*C02;
        q10 = ha*q10 + hb*C10; q11 = ha*q11 + hb*C11; q12 = ha*q12 + hb*C12;
        q20 = ha*q20 + hb*C20; q21 = ha*q21 + hb*C21; q22 = ha*q22 + hb*C22;
    }

    // tr(P) = <Q, A>_F with A = Mc^T  (sum of singular values of Mc)
    float trP = q00*c00 + q01*c10 + q02*c20
              + q10*c01 + q11*c11 + q12*c21
              + q20*c02 + q21*c12 + q22*c22;
    // Z_j = (trP/||Y0||^2) * sum_i (y_i - muY_i) Q_ij + muX_j   (normX cancels)
    float k = trP / ny2;
    float r00=k*q00, r01=k*q01, r02=k*q02;
    float r10=k*q10, r11=k*q11, r12=k*q12;
    float r20=k*q20, r21=k*q21, r22=k*q22;

    // ---- per-joint error ----
    float errsum = 0.0f;
    #pragma unroll
    for (int n = 0; n < NPTS; ++n) {
        float xa = sbuf[base + 3*n + 0];
        float xb = sbuf[base + 3*n + 1];
        float xc = sbuf[base + 3*n + 2];
        float u = y[n][0] - muy0, v = y[n][1] - muy1, w = y[n][2] - muy2;
        float z0 = fmaf(u, r00, fmaf(v, r10, fmaf(w, r20, mux0))) - xa;
        float z1 = fmaf(u, r01, fmaf(v, r11, fmaf(w, r21, mux1))) - xb;
        float z2 = fmaf(u, r02, fmaf(v, r12, fmaf(w, r22, mux2))) - xc;
        errsum += sqrtf(fmaf(z0, z0, fmaf(z1, z1, z2*z2)));
    }
    if (tid >= nb) errsum = 0.0f;

    // ---- block reduction: wave shuffle -> LDS -> one atomic per block ----
    #pragma unroll
    for (int off = 32; off > 0; off >>= 1) errsum += __shfl_down(errsum, off, 64);
    if ((tid & 63) == 0) swsum[tid >> 6] = errsum;
    __syncthreads();
    if (tid == 0) {
        float tot = swsum[0];
        #pragma unroll
        for (int wv = 1; wv < THREADS / 64; ++wv) tot += swsum[wv];
        atomicAdd(out, tot * inv_total);
    }
}

extern "C" void kernel_launch(void* const* d_in, const int* in_sizes, int n_in,
                              void* d_out, int out_size, void* d_ws, size_t ws_size,
                              hipStream_t stream)
{
    const float* pred = (const float*)d_in[0];   // pred_kp3d  [B,21,3] f32
    const float* targ = (const float*)d_in[1];   // target_kp3d [B,21,3] f32
    float* out = (float*)d_out;

    int B = in_sizes[0] / FLB;
    float inv_total = 1.0f / ((float)B * (float)NPTS);

    pa_init<<<1, 64, 0, stream>>>(out);   // d_out is poisoned 0xAA before every launch
    int grid = (B + BPB - 1) / BPB;
    pa_mpjpe<<<grid, THREADS, 0, stream>>>(pred, targ, out, B, inv_total);
}